// Round 4
// baseline (224.013 us; speedup 1.0000x reference)
//
#include <hip/hip_runtime.h>

// Problem constants
#define BATCH   2
#define NPTS    2048
#define MPTS    512
#define BM_TOT  1024     // BATCH*MPTS
#define GVOX    27
#define CRED    32
#define CIG     41       // CRED + 9
#define CAGG    32
#define GCH     864      // GVOX*CAGG
#define CPOST   128
#define QRF     4.8f
#define MULT    1.6000000238418579f   // f32(2.0*2.4/3.0)

// d_ws float layout
#define WS_XBUF  0                      // 1024*864
#define WS_WT    884736                 // 27*41*32 = 35424  (transposed, BN1-scaled)
#define WS_BB1   920160                 // 864
#define WS_WP2   921024                 // 128*864 (BN2-scaled)
#define WS_BB2   1031616                // 128

// ---------------------------------------------------------------------------
// Prep: fold BN1 into transposed group weights, BN2 into w_post
// ---------------------------------------------------------------------------
__global__ __launch_bounds__(256) void vpa_prep(
    const float* __restrict__ wgrp,
    const float* __restrict__ g1, const float* __restrict__ b1,
    const float* __restrict__ m1, const float* __restrict__ v1,
    const float* __restrict__ wp,
    const float* __restrict__ g2, const float* __restrict__ b2,
    const float* __restrict__ m2, const float* __restrict__ v2,
    float* __restrict__ ws)
{
    const int idx = blockIdx.x * 256 + threadIdx.x;
    if (idx < 35424) {                       // wT[g][i][o] = wgrp[g][o][i]*sc1
        const int o = idx & 31;
        const int r = idx >> 5;              // g*41 + i
        const int g = r / 41;
        const int ch = g * CAGG + o;
        const float sc = g1[ch] * rsqrtf(v1[ch] + 1e-5f);
        ws[WS_WT + idx] = wgrp[ch * CIG + (r - g * 41)] * sc;
    }
    int j = idx - 35424;
    if (j >= 0 && j < GCH) {                 // bb1
        const float sc = g1[j] * rsqrtf(v1[j] + 1e-5f);
        ws[WS_BB1 + j] = b1[j] - sc * m1[j];
    }
    j = idx - (35424 + GCH);
    if (j >= 0 && j < CPOST * GCH) {         // wp2[o][i] = wp[o][i]*sc2[o]
        const int o = j / GCH;
        const float sc = g2[o] * rsqrtf(v2[o] + 1e-5f);
        ws[WS_WP2 + j] = wp[j] * sc;
    }
    j = idx - (35424 + GCH + CPOST * GCH);
    if (j >= 0 && j < CPOST) {               // bb2
        const float sc = g2[j] * rsqrtf(v2[j] + 1e-5f);
        ws[WS_BB2 + j] = b2[j] - sc * m2[j];
    }
}

// lexicographic (d, idx) sorted-3 insert
__device__ __forceinline__ void merge3(float& d0, float& d1, float& d2,
                                       int& i0, int& i1, int& i2,
                                       float e, int jj) {
    const bool c0 = (e < d0) || (e == d0 && jj < i0);
    const bool c1 = (e < d1) || (e == d1 && jj < i1);
    const bool c2 = (e < d2) || (e == d2 && jj < i2);
    d2 = c1 ? d1 : (c2 ? e : d2);  i2 = c1 ? i1 : (c2 ? jj : i2);
    d1 = c0 ? d0 : (c1 ? e : d1);  i1 = c0 ? i0 : (c1 ? jj : i1);
    d0 = c0 ? e : d0;              i0 = c0 ? jj : i0;
}

// ---------------------------------------------------------------------------
// Kernel 1: 3-NN + interpolation + grouped conv (+folded BN1+ReLU)
// block = one target point m; wave wv owns voxels g = wv+4t, t=0..6
// ---------------------------------------------------------------------------
__global__ __launch_bounds__(256, 4) void vpa_main(
    const float* __restrict__ sxyz,
    const float* __restrict__ sfeat,
    const float* __restrict__ nxyz,
    const float* __restrict__ ws,     // wT, bb1
    float* __restrict__ xout)
{
    __shared__ float spts[NPTS * 3];  // 24 KB

    const int m    = blockIdx.x;
    const int b    = m >> 9;
    const int tid  = threadIdx.x;
    const int lane = tid & 63;
    const int wv   = tid >> 6;

    const float* sx = sxyz + b * (NPTS * 3);
    for (int j = tid; j < NPTS * 3; j += 256) spts[j] = sx[j];

    const float nx = nxyz[m * 3 + 0];
    const float ny = nxyz[m * 3 + 1];
    const float nz = nxyz[m * 3 + 2];
    __syncthreads();

    const float INF = __builtin_inff();
    const float* wT  = ws + WS_WT;
    const float* bb1 = ws + WS_BB1;

    float cxa[7], cya[7], cza[7];
    float bd[7][3];
    int   bi[7][3];

    #pragma unroll
    for (int t = 0; t < 7; ++t) {
        const int g = wv + 4 * t;
        if (g < GVOX) {
            const int gi = g / 9, rem = g - gi * 9;
            const int gj = rem / 3, gk = rem - gj * 3;
            cxa[t] = nx + (((float)gi + 0.5f) * MULT - 2.4f);
            cya[t] = ny + (((float)gj + 0.5f) * MULT - 2.4f);
            cza[t] = nz + (((float)gk + 0.5f) * MULT - 2.4f);
        } else {
            cxa[t] = cya[t] = cza[t] = 1e18f;  // gated out by cheby test
        }
        bd[t][0] = bd[t][1] = bd[t][2] = INF;
        bi[t][0] = bi[t][1] = bi[t][2] = 0x7fffffff;
    }

    // scan: load each point once, update all 7 voxels
    for (int k = 0; k < 32; ++k) {
        const int p  = (k << 6) + lane;
        const int p3 = p * 3;
        const float px = spts[p3 + 0];
        const float py = spts[p3 + 1];
        const float pz = spts[p3 + 2];
        #pragma unroll
        for (int t = 0; t < 7; ++t) {
            const float dx = cxa[t] - px;
            const float dy = cya[t] - py;
            const float dz = cza[t] - pz;
            float dd = __fadd_rn(__fadd_rn(__fmul_rn(dx, dx),
                                           __fmul_rn(dy, dy)),
                                 __fmul_rn(dz, dz));
            const float ch = fmaxf(fmaxf(fabsf(dx), fabsf(dy)), fabsf(dz));
            dd = (ch <= QRF) ? dd : INF;
            const bool c0 = dd < bd[t][0], c1 = dd < bd[t][1], c2 = dd < bd[t][2];
            bd[t][2] = c1 ? bd[t][1] : (c2 ? dd : bd[t][2]);
            bi[t][2] = c1 ? bi[t][1] : (c2 ? p  : bi[t][2]);
            bd[t][1] = c0 ? bd[t][0] : (c1 ? dd : bd[t][1]);
            bi[t][1] = c0 ? bi[t][0] : (c1 ? p  : bi[t][1]);
            bd[t][0] = c0 ? dd : bd[t][0];
            bi[t][0] = c0 ? p  : bi[t][0];
        }
    }

    // per-voxel: wave merge, interpolation, grouped conv (no block barriers)
    #pragma unroll
    for (int t = 0; t < 7; ++t) {
        const int g = wv + 4 * t;       // wave-uniform
        if (g < GVOX) {
            float d0 = bd[t][0], d1 = bd[t][1], d2 = bd[t][2];
            int   i0 = bi[t][0], i1 = bi[t][1], i2 = bi[t][2];

            for (int s = 1; s < 64; s <<= 1) {
                const float e0 = __shfl_xor(d0, s);
                const float e1 = __shfl_xor(d1, s);
                const float e2 = __shfl_xor(d2, s);
                const int   j0 = __shfl_xor(i0, s);
                const int   j1 = __shfl_xor(i1, s);
                const int   j2 = __shfl_xor(i2, s);
                merge3(d0, d1, d2, i0, i1, i2, e0, j0);
                merge3(d0, d1, d2, i0, i1, i2, e1, j1);
                merge3(d0, d1, d2, i0, i1, i2, e2, j2);
            }

            const float r0 = 1.0f / (d0 + 1e-8f);
            const float r1 = 1.0f / (d1 + 1e-8f);
            const float r2 = 1.0f / (d2 + 1e-8f);
            const float rs = fmaxf((r0 + r1) + r2, 1e-8f);
            const float w0 = r0 / rs, w1 = r1 / rs, w2 = r2 / rs;
            const bool  empty = !(d0 < INF);
            const int s0 = (i0 < NPTS) ? i0 : 0;
            const int s1 = (i1 < NPTS) ? i1 : 0;
            const int s2 = (i2 < NPTS) ? i2 : 0;

            float fval = 0.0f;
            if (lane < CRED) {
                const float* Fb = sfeat + b * (NPTS * 128) + lane;
                const float* p0 = Fb + s0 * 128;
                const float* p1 = Fb + s1 * 128;
                const float* p2 = Fb + s2 * 128;
                const float f0 = ((p0[0] + p0[32]) + p0[64]) + p0[96];
                const float f1 = ((p1[0] + p1[32]) + p1[64]) + p1[96];
                const float f2 = ((p2[0] + p2[32]) + p2[64]) + p2[96];
                fval = (w0 * f0 + w1 * f1) + w2 * f2;
            } else if (lane < CIG) {
                const int j  = lane - 32;
                const int kk = j / 3, ax = j - 3 * kk;
                const int ik = (kk == 0) ? s0 : ((kk == 1) ? s1 : s2);
                const float cc = (ax == 0) ? cxa[t] : ((ax == 1) ? cya[t] : cza[t]);
                fval = cc - spts[ik * 3 + ax];
            }
            if (empty) fval = 0.0f;

            // conv: lane ch accumulates over 41 inputs; shfl broadcasts are
            // executed by ALL lanes (uniform control flow), weight address
            // clamped with (lane&31) so lanes 32..63 stay in bounds.
            float acc = 0.0f;
            const float* wrow = wT + g * (CIG * CAGG) + (lane & 31);
            #pragma unroll
            for (int i = 0; i < CIG; ++i) {
                const float bc = __shfl(fval, i);
                acc += bc * wrow[i * CAGG];
            }
            if (lane < CAGG) {
                const int ch = g * CAGG + lane;
                xout[m * GCH + ch] = fmaxf(acc + bb1[ch], 0.0f);
            }
        }
    }
}

// ---------------------------------------------------------------------------
// Kernel 2: post MLP  out = relu(x @ wp2^T + bb2)
// block = 4 rows; threads = (il = i-lane 0..15) x (og = 0..15); o = oo*16+og
// ---------------------------------------------------------------------------
__global__ __launch_bounds__(256) void vpa_post(
    const float* __restrict__ xin,    // (1024,864)
    const float* __restrict__ ws,     // wp2, bb2
    float* __restrict__ out)          // (1024,128)
{
    __shared__ __align__(16) float xs[4 * GCH];   // 13.8 KB

    const int mb  = blockIdx.x * 4;
    const int tid = threadIdx.x;
    const float* wp2 = ws + WS_WP2;
    const float* bb2 = ws + WS_BB2;

    for (int j = tid; j < 4 * GCH; j += 256) xs[j] = xin[mb * GCH + j];
    __syncthreads();

    const int il = tid & 15;          // i-lane
    const int og = tid >> 4;          // 0..15

    float acc[8][4];
    #pragma unroll
    for (int oo = 0; oo < 8; ++oo)
        #pragma unroll
        for (int mm = 0; mm < 4; ++mm) acc[oo][mm] = 0.0f;

    for (int jj = 0; jj < 14; ++jj) {
        const int i4 = il + 16 * jj;
        if (i4 < 216) {
            const int i = i4 * 4;
            const float4 x0 = *(const float4*)&xs[0 * GCH + i];
            const float4 x1 = *(const float4*)&xs[1 * GCH + i];
            const float4 x2 = *(const float4*)&xs[2 * GCH + i];
            const float4 x3 = *(const float4*)&xs[3 * GCH + i];
            #pragma unroll
            for (int oo = 0; oo < 8; ++oo) {
                const int o = oo * 16 + og;
                const float4 w = *(const float4*)&wp2[o * GCH + i];
                acc[oo][0] += x0.x * w.x + x0.y * w.y + x0.z * w.z + x0.w * w.w;
                acc[oo][1] += x1.x * w.x + x1.y * w.y + x1.z * w.z + x1.w * w.w;
                acc[oo][2] += x2.x * w.x + x2.y * w.y + x2.z * w.z + x2.w * w.w;
                acc[oo][3] += x3.x * w.x + x3.y * w.y + x3.z * w.z + x3.w * w.w;
            }
        }
    }

    // reduce over the 16 i-lanes (lanes grouped 16-consecutive per og)
    #pragma unroll
    for (int s = 1; s < 16; s <<= 1)
        #pragma unroll
        for (int oo = 0; oo < 8; ++oo)
            #pragma unroll
            for (int mm = 0; mm < 4; ++mm)
                acc[oo][mm] += __shfl_xor(acc[oo][mm], s);

    if (il == 0) {
        #pragma unroll
        for (int oo = 0; oo < 8; ++oo) {
            const int o = oo * 16 + og;
            const float bias = bb2[o];
            #pragma unroll
            for (int mm = 0; mm < 4; ++mm)
                out[(mb + mm) * CPOST + o] = fmaxf(acc[oo][mm] + bias, 0.0f);
        }
    }
}

// ---------------------------------------------------------------------------
extern "C" void kernel_launch(void* const* d_in, const int* in_sizes, int n_in,
                              void* d_out, int out_size, void* d_ws, size_t ws_size,
                              hipStream_t stream) {
    const float* sxyz  = (const float*)d_in[0];
    const float* sfeat = (const float*)d_in[1];
    const float* nxyz  = (const float*)d_in[2];
    const float* wgrp  = (const float*)d_in[3];
    const float* g1    = (const float*)d_in[4];
    const float* b1    = (const float*)d_in[5];
    const float* m1    = (const float*)d_in[6];
    const float* v1    = (const float*)d_in[7];
    const float* wp    = (const float*)d_in[8];
    const float* g2    = (const float*)d_in[9];
    const float* b2    = (const float*)d_in[10];
    const float* m2    = (const float*)d_in[11];
    const float* v2    = (const float*)d_in[12];

    float* ws   = (float*)d_ws;
    float* xbuf = ws + WS_XBUF;
    float* outp = (float*)d_out;

    hipLaunchKernelGGL(vpa_prep, dim3(575), dim3(256), 0, stream,
                       wgrp, g1, b1, m1, v1, wp, g2, b2, m2, v2, ws);
    hipLaunchKernelGGL(vpa_main, dim3(BM_TOT), dim3(256), 0, stream,
                       sxyz, sfeat, nxyz, ws, xbuf);
    hipLaunchKernelGGL(vpa_post, dim3(BM_TOT / 4), dim3(256), 0, stream,
                       xbuf, ws, outp);
}

// Round 5
// 216.772 us; speedup vs baseline: 1.0334x; 1.0334x over previous
//
#include <hip/hip_runtime.h>

// Problem constants
#define BATCH   2
#define NPTS    2048
#define MPTS    512
#define BM_TOT  1024     // BATCH*MPTS
#define GVOX    27
#define CRED    32
#define CIG     41       // CRED + 9
#define CAGG    32
#define GCH     864      // GVOX*CAGG
#define CPOST   128
#define QRF     4.8f
#define MULT    1.6000000238418579f   // f32(2.0*2.4/3.0)

// d_ws float layout
#define WS_XBUF  0                      // 1024*864
#define WS_WT    884736                 // 27*41*32 = 35424  (transposed, BN1-scaled)
#define WS_BB1   920160                 // 864
#define WS_WP2   921024                 // 128*864 (BN2-scaled)
#define WS_BB2   1031616                // 128

// ---------------------------------------------------------------------------
// Prep: fold BN1 into transposed group weights, BN2 into w_post
// ---------------------------------------------------------------------------
__global__ __launch_bounds__(256) void vpa_prep(
    const float* __restrict__ wgrp,
    const float* __restrict__ g1, const float* __restrict__ b1,
    const float* __restrict__ m1, const float* __restrict__ v1,
    const float* __restrict__ wp,
    const float* __restrict__ g2, const float* __restrict__ b2,
    const float* __restrict__ m2, const float* __restrict__ v2,
    float* __restrict__ ws)
{
    const int idx = blockIdx.x * 256 + threadIdx.x;
    if (idx < 35424) {                       // wT[g][i][o] = wgrp[g][o][i]*sc1
        const int o = idx & 31;
        const int r = idx >> 5;              // g*41 + i
        const int g = r / 41;
        const int ch = g * CAGG + o;
        const float sc = g1[ch] * rsqrtf(v1[ch] + 1e-5f);
        ws[WS_WT + idx] = wgrp[ch * CIG + (r - g * 41)] * sc;
    }
    int j = idx - 35424;
    if (j >= 0 && j < GCH) {                 // bb1
        const float sc = g1[j] * rsqrtf(v1[j] + 1e-5f);
        ws[WS_BB1 + j] = b1[j] - sc * m1[j];
    }
    j = idx - (35424 + GCH);
    if (j >= 0 && j < CPOST * GCH) {         // wp2[o][i] = wp[o][i]*sc2[o]
        const int o = j / GCH;
        const float sc = g2[o] * rsqrtf(v2[o] + 1e-5f);
        ws[WS_WP2 + j] = wp[j] * sc;
    }
    j = idx - (35424 + GCH + CPOST * GCH);
    if (j >= 0 && j < CPOST) {               // bb2
        const float sc = g2[j] * rsqrtf(v2[j] + 1e-5f);
        ws[WS_BB2 + j] = b2[j] - sc * m2[j];
    }
}

// lexicographic (d, idx) sorted-3 insert
__device__ __forceinline__ void merge3(float& d0, float& d1, float& d2,
                                       int& i0, int& i1, int& i2,
                                       float e, int jj) {
    const bool c0 = (e < d0) || (e == d0 && jj < i0);
    const bool c1 = (e < d1) || (e == d1 && jj < i1);
    const bool c2 = (e < d2) || (e == d2 && jj < i2);
    d2 = c1 ? d1 : (c2 ? e : d2);  i2 = c1 ? i1 : (c2 ? jj : i2);
    d1 = c0 ? d0 : (c1 ? e : d1);  i1 = c0 ? i0 : (c1 ? jj : i1);
    d0 = c0 ? e : d0;              i0 = c0 ? jj : i0;
}

// ---------------------------------------------------------------------------
// Kernel 1: 3-NN + interpolation + grouped conv (+folded BN1+ReLU)
// block = one target point m; wave wv owns voxels g = wv+4t, t=0..6
// amdgpu_waves_per_eu(4,4): pin 128-VGPR budget — r4 showed the compiler
// squeezing to 64 VGPRs and spilling 16 dwords/thread (16 MiB WRITE_SIZE).
// ---------------------------------------------------------------------------
__global__ __launch_bounds__(256)
__attribute__((amdgpu_waves_per_eu(4, 4)))
void vpa_main(
    const float* __restrict__ sxyz,
    const float* __restrict__ sfeat,
    const float* __restrict__ nxyz,
    const float* __restrict__ ws,     // wT, bb1
    float* __restrict__ xout)
{
    __shared__ float spts[NPTS * 3];  // 24 KB

    const int m    = blockIdx.x;
    const int b    = m >> 9;
    const int tid  = threadIdx.x;
    const int lane = tid & 63;
    const int wv   = tid >> 6;

    const float* sx = sxyz + b * (NPTS * 3);
    for (int j = tid; j < NPTS * 3; j += 256) spts[j] = sx[j];

    const float nx = nxyz[m * 3 + 0];
    const float ny = nxyz[m * 3 + 1];
    const float nz = nxyz[m * 3 + 2];
    __syncthreads();

    const float INF = __builtin_inff();
    const float* wT  = ws + WS_WT;
    const float* bb1 = ws + WS_BB1;

    float cxa[7], cya[7], cza[7];
    float bd[7][3];
    int   bi[7][3];

    #pragma unroll
    for (int t = 0; t < 7; ++t) {
        const int g = wv + 4 * t;
        if (g < GVOX) {
            const int gi = g / 9, rem = g - gi * 9;
            const int gj = rem / 3, gk = rem - gj * 3;
            cxa[t] = nx + (((float)gi + 0.5f) * MULT - 2.4f);
            cya[t] = ny + (((float)gj + 0.5f) * MULT - 2.4f);
            cza[t] = nz + (((float)gk + 0.5f) * MULT - 2.4f);
        } else {
            cxa[t] = cya[t] = cza[t] = 1e18f;  // gated out by cheby test
        }
        bd[t][0] = bd[t][1] = bd[t][2] = INF;
        bi[t][0] = bi[t][1] = bi[t][2] = 0x7fffffff;
    }

    // scan: load each point once, update all 7 voxels
    for (int k = 0; k < 32; ++k) {
        const int p  = (k << 6) + lane;
        const int p3 = p * 3;
        const float px = spts[p3 + 0];
        const float py = spts[p3 + 1];
        const float pz = spts[p3 + 2];
        #pragma unroll
        for (int t = 0; t < 7; ++t) {
            const float dx = cxa[t] - px;
            const float dy = cya[t] - py;
            const float dz = cza[t] - pz;
            float dd = __fadd_rn(__fadd_rn(__fmul_rn(dx, dx),
                                           __fmul_rn(dy, dy)),
                                 __fmul_rn(dz, dz));
            const float ch = fmaxf(fmaxf(fabsf(dx), fabsf(dy)), fabsf(dz));
            dd = (ch <= QRF) ? dd : INF;
            const bool c0 = dd < bd[t][0], c1 = dd < bd[t][1], c2 = dd < bd[t][2];
            bd[t][2] = c1 ? bd[t][1] : (c2 ? dd : bd[t][2]);
            bi[t][2] = c1 ? bi[t][1] : (c2 ? p  : bi[t][2]);
            bd[t][1] = c0 ? bd[t][0] : (c1 ? dd : bd[t][1]);
            bi[t][1] = c0 ? bi[t][0] : (c1 ? p  : bi[t][1]);
            bd[t][0] = c0 ? dd : bd[t][0];
            bi[t][0] = c0 ? p  : bi[t][0];
        }
    }

    // per-voxel: wave merge, interpolation, grouped conv (no block barriers)
    #pragma unroll
    for (int t = 0; t < 7; ++t) {
        const int g = wv + 4 * t;       // wave-uniform
        if (g < GVOX) {
            float d0 = bd[t][0], d1 = bd[t][1], d2 = bd[t][2];
            int   i0 = bi[t][0], i1 = bi[t][1], i2 = bi[t][2];

            for (int s = 1; s < 64; s <<= 1) {
                const float e0 = __shfl_xor(d0, s);
                const float e1 = __shfl_xor(d1, s);
                const float e2 = __shfl_xor(d2, s);
                const int   j0 = __shfl_xor(i0, s);
                const int   j1 = __shfl_xor(i1, s);
                const int   j2 = __shfl_xor(i2, s);
                merge3(d0, d1, d2, i0, i1, i2, e0, j0);
                merge3(d0, d1, d2, i0, i1, i2, e1, j1);
                merge3(d0, d1, d2, i0, i1, i2, e2, j2);
            }

            const float r0 = 1.0f / (d0 + 1e-8f);
            const float r1 = 1.0f / (d1 + 1e-8f);
            const float r2 = 1.0f / (d2 + 1e-8f);
            const float rs = fmaxf((r0 + r1) + r2, 1e-8f);
            const float w0 = r0 / rs, w1 = r1 / rs, w2 = r2 / rs;
            const bool  empty = !(d0 < INF);
            const int s0 = (i0 < NPTS) ? i0 : 0;
            const int s1 = (i1 < NPTS) ? i1 : 0;
            const int s2 = (i2 < NPTS) ? i2 : 0;

            float fval = 0.0f;
            if (lane < CRED) {
                const float* Fb = sfeat + b * (NPTS * 128) + lane;
                const float* p0 = Fb + s0 * 128;
                const float* p1 = Fb + s1 * 128;
                const float* p2 = Fb + s2 * 128;
                const float f0 = ((p0[0] + p0[32]) + p0[64]) + p0[96];
                const float f1 = ((p1[0] + p1[32]) + p1[64]) + p1[96];
                const float f2 = ((p2[0] + p2[32]) + p2[64]) + p2[96];
                fval = (w0 * f0 + w1 * f1) + w2 * f2;
            } else if (lane < CIG) {
                const int j  = lane - 32;
                const int kk = j / 3, ax = j - 3 * kk;
                const int ik = (kk == 0) ? s0 : ((kk == 1) ? s1 : s2);
                const float cc = (ax == 0) ? cxa[t] : ((ax == 1) ? cya[t] : cza[t]);
                fval = cc - spts[ik * 3 + ax];
            }
            if (empty) fval = 0.0f;

            // conv: lane ch accumulates over 41 inputs; shfl broadcasts are
            // executed by ALL lanes (uniform control flow), weight address
            // clamped with (lane&31) so lanes 32..63 stay in bounds.
            float acc = 0.0f;
            const float* wrow = wT + g * (CIG * CAGG) + (lane & 31);
            #pragma unroll
            for (int i = 0; i < CIG; ++i) {
                const float bc = __shfl(fval, i);
                acc += bc * wrow[i * CAGG];
            }
            if (lane < CAGG) {
                const int ch = g * CAGG + lane;
                xout[m * GCH + ch] = fmaxf(acc + bb1[ch], 0.0f);
            }
        }
    }
}

// ---------------------------------------------------------------------------
// Kernel 2: post MLP  out = relu(x @ wp2^T + bb2)
// block = 4 rows; threads = (il = i-lane 0..15) x (og = 0..15); o = oo*16+og
// waves_per_eu(4,4): acc[8][4]+float4 temps ~60 regs — same anti-spill pin.
// ---------------------------------------------------------------------------
__global__ __launch_bounds__(256)
__attribute__((amdgpu_waves_per_eu(4, 4)))
void vpa_post(
    const float* __restrict__ xin,    // (1024,864)
    const float* __restrict__ ws,     // wp2, bb2
    float* __restrict__ out)          // (1024,128)
{
    __shared__ __align__(16) float xs[4 * GCH];   // 13.8 KB

    const int mb  = blockIdx.x * 4;
    const int tid = threadIdx.x;
    const float* wp2 = ws + WS_WP2;
    const float* bb2 = ws + WS_BB2;

    for (int j = tid; j < 4 * GCH; j += 256) xs[j] = xin[mb * GCH + j];
    __syncthreads();

    const int il = tid & 15;          // i-lane
    const int og = tid >> 4;          // 0..15

    float acc[8][4];
    #pragma unroll
    for (int oo = 0; oo < 8; ++oo)
        #pragma unroll
        for (int mm = 0; mm < 4; ++mm) acc[oo][mm] = 0.0f;

    for (int jj = 0; jj < 14; ++jj) {
        const int i4 = il + 16 * jj;
        if (i4 < 216) {
            const int i = i4 * 4;
            const float4 x0 = *(const float4*)&xs[0 * GCH + i];
            const float4 x1 = *(const float4*)&xs[1 * GCH + i];
            const float4 x2 = *(const float4*)&xs[2 * GCH + i];
            const float4 x3 = *(const float4*)&xs[3 * GCH + i];
            #pragma unroll
            for (int oo = 0; oo < 8; ++oo) {
                const int o = oo * 16 + og;
                const float4 w = *(const float4*)&wp2[o * GCH + i];
                acc[oo][0] += x0.x * w.x + x0.y * w.y + x0.z * w.z + x0.w * w.w;
                acc[oo][1] += x1.x * w.x + x1.y * w.y + x1.z * w.z + x1.w * w.w;
                acc[oo][2] += x2.x * w.x + x2.y * w.y + x2.z * w.z + x2.w * w.w;
                acc[oo][3] += x3.x * w.x + x3.y * w.y + x3.z * w.z + x3.w * w.w;
            }
        }
    }

    // reduce over the 16 i-lanes (lanes grouped 16-consecutive per og)
    #pragma unroll
    for (int s = 1; s < 16; s <<= 1)
        #pragma unroll
        for (int oo = 0; oo < 8; ++oo)
            #pragma unroll
            for (int mm = 0; mm < 4; ++mm)
                acc[oo][mm] += __shfl_xor(acc[oo][mm], s);

    if (il == 0) {
        #pragma unroll
        for (int oo = 0; oo < 8; ++oo) {
            const int o = oo * 16 + og;
            const float bias = bb2[o];
            #pragma unroll
            for (int mm = 0; mm < 4; ++mm)
                out[(mb + mm) * CPOST + o] = fmaxf(acc[oo][mm] + bias, 0.0f);
        }
    }
}

// ---------------------------------------------------------------------------
extern "C" void kernel_launch(void* const* d_in, const int* in_sizes, int n_in,
                              void* d_out, int out_size, void* d_ws, size_t ws_size,
                              hipStream_t stream) {
    const float* sxyz  = (const float*)d_in[0];
    const float* sfeat = (const float*)d_in[1];
    const float* nxyz  = (const float*)d_in[2];
    const float* wgrp  = (const float*)d_in[3];
    const float* g1    = (const float*)d_in[4];
    const float* b1    = (const float*)d_in[5];
    const float* m1    = (const float*)d_in[6];
    const float* v1    = (const float*)d_in[7];
    const float* wp    = (const float*)d_in[8];
    const float* g2    = (const float*)d_in[9];
    const float* b2    = (const float*)d_in[10];
    const float* m2    = (const float*)d_in[11];
    const float* v2    = (const float*)d_in[12];

    float* ws   = (float*)d_ws;
    float* xbuf = ws + WS_XBUF;
    float* outp = (float*)d_out;

    hipLaunchKernelGGL(vpa_prep, dim3(575), dim3(256), 0, stream,
                       wgrp, g1, b1, m1, v1, wp, g2, b2, m2, v2, ws);
    hipLaunchKernelGGL(vpa_main, dim3(BM_TOT), dim3(256), 0, stream,
                       sxyz, sfeat, nxyz, ws, xbuf);
    hipLaunchKernelGGL(vpa_post, dim3(BM_TOT / 4), dim3(256), 0, stream,
                       xbuf, ws, outp);
}

// Round 6
// 212.569 us; speedup vs baseline: 1.0538x; 1.0198x over previous
//
#include <hip/hip_runtime.h>

// Problem constants
#define BATCH   2
#define NPTS    2048
#define MPTS    512
#define BM_TOT  1024     // BATCH*MPTS
#define GVOX    27
#define CRED    32
#define CIG     41       // CRED + 9
#define CAGG    32
#define GCH     864      // GVOX*CAGG
#define CPOST   128
#define QRF     4.8f
#define MULT    1.6000000238418579f   // f32(2.0*2.4/3.0)

// d_ws float layout
#define WS_XBUF  0                      // 1024*864
#define WS_WT    884736                 // 27*41*32 = 35424  (transposed, BN1-scaled)
#define WS_BB1   920160                 // 864
#define WS_WP2   921024                 // 128*864 (BN2-scaled)
#define WS_BB2   1031616                // 128

// ---------------------------------------------------------------------------
// Prep: fold BN1 into transposed group weights, BN2 into w_post
// ---------------------------------------------------------------------------
__global__ __launch_bounds__(256) void vpa_prep(
    const float* __restrict__ wgrp,
    const float* __restrict__ g1, const float* __restrict__ b1,
    const float* __restrict__ m1, const float* __restrict__ v1,
    const float* __restrict__ wp,
    const float* __restrict__ g2, const float* __restrict__ b2,
    const float* __restrict__ m2, const float* __restrict__ v2,
    float* __restrict__ ws)
{
    const int idx = blockIdx.x * 256 + threadIdx.x;
    if (idx < 35424) {                       // wT[g][i][o] = wgrp[g][o][i]*sc1
        const int o = idx & 31;
        const int r = idx >> 5;              // g*41 + i
        const int g = r / 41;
        const int ch = g * CAGG + o;
        const float sc = g1[ch] * rsqrtf(v1[ch] + 1e-5f);
        ws[WS_WT + idx] = wgrp[ch * CIG + (r - g * 41)] * sc;
    }
    int j = idx - 35424;
    if (j >= 0 && j < GCH) {                 // bb1
        const float sc = g1[j] * rsqrtf(v1[j] + 1e-5f);
        ws[WS_BB1 + j] = b1[j] - sc * m1[j];
    }
    j = idx - (35424 + GCH);
    if (j >= 0 && j < CPOST * GCH) {         // wp2[o][i] = wp[o][i]*sc2[o]
        const int o = j / GCH;
        const float sc = g2[o] * rsqrtf(v2[o] + 1e-5f);
        ws[WS_WP2 + j] = wp[j] * sc;
    }
    j = idx - (35424 + GCH + CPOST * GCH);
    if (j >= 0 && j < CPOST) {               // bb2
        const float sc = g2[j] * rsqrtf(v2[j] + 1e-5f);
        ws[WS_BB2 + j] = b2[j] - sc * m2[j];
    }
}

// lexicographic (d, idx) sorted-3 insert
__device__ __forceinline__ void merge3(float& d0, float& d1, float& d2,
                                       int& i0, int& i1, int& i2,
                                       float e, int jj) {
    const bool c0 = (e < d0) || (e == d0 && jj < i0);
    const bool c1 = (e < d1) || (e == d1 && jj < i1);
    const bool c2 = (e < d2) || (e == d2 && jj < i2);
    d2 = c1 ? d1 : (c2 ? e : d2);  i2 = c1 ? i1 : (c2 ? jj : i2);
    d1 = c0 ? d0 : (c1 ? e : d1);  i1 = c0 ? i0 : (c1 ? jj : i1);
    d0 = c0 ? e : d0;              i0 = c0 ? jj : i0;
}

// ---------------------------------------------------------------------------
// One batch of BS voxels (t = T0..T0+BS-1) for wave wv: scan LDS points,
// wave-merge, interpolate, grouped conv, store. Batching keeps live state
// (~6*BS + 3*BS regs) under the 64-VGPR budget — r4/r5 showed 7-voxel state
// (63 regs) spills 16 dwords/thread (16 MiB of scratch WRITE).
// ---------------------------------------------------------------------------
template<int BS, int T0>
__device__ __forceinline__ void process_batch(
    const int wv, const int lane, const int b, const int m,
    const float nx, const float ny, const float nz,
    const float* __restrict__ spts,
    const float* __restrict__ sfeat,
    const float* __restrict__ wT,
    const float* __restrict__ bb1,
    float* __restrict__ xout)
{
    const float INF = __builtin_inff();

    float cx[BS], cy[BS], cz[BS];
    float bd[BS][3];
    int   bi[BS][3];

    #pragma unroll
    for (int j = 0; j < BS; ++j) {
        const int g = wv + 4 * (T0 + j);
        if (g < GVOX) {
            const int gi = g / 9, rem = g - gi * 9;
            const int gj = rem / 3, gk = rem - gj * 3;
            cx[j] = nx + (((float)gi + 0.5f) * MULT - 2.4f);
            cy[j] = ny + (((float)gj + 0.5f) * MULT - 2.4f);
            cz[j] = nz + (((float)gk + 0.5f) * MULT - 2.4f);
        } else {
            cx[j] = cy[j] = cz[j] = 1e18f;   // gated out by cheby test
        }
        bd[j][0] = bd[j][1] = bd[j][2] = INF;
        bi[j][0] = bi[j][1] = bi[j][2] = 0x7fffffff;
    }

    // scan: load each point once, update BS voxels
    for (int k = 0; k < 32; ++k) {
        const int p  = (k << 6) + lane;
        const int p3 = p * 3;
        const float px = spts[p3 + 0];
        const float py = spts[p3 + 1];
        const float pz = spts[p3 + 2];
        #pragma unroll
        for (int j = 0; j < BS; ++j) {
            const float dx = cx[j] - px;
            const float dy = cy[j] - py;
            const float dz = cz[j] - pz;
            float dd = __fadd_rn(__fadd_rn(__fmul_rn(dx, dx),
                                           __fmul_rn(dy, dy)),
                                 __fmul_rn(dz, dz));
            const float ch = fmaxf(fmaxf(fabsf(dx), fabsf(dy)), fabsf(dz));
            dd = (ch <= QRF) ? dd : INF;
            const bool c0 = dd < bd[j][0], c1 = dd < bd[j][1], c2 = dd < bd[j][2];
            bd[j][2] = c1 ? bd[j][1] : (c2 ? dd : bd[j][2]);
            bi[j][2] = c1 ? bi[j][1] : (c2 ? p  : bi[j][2]);
            bd[j][1] = c0 ? bd[j][0] : (c1 ? dd : bd[j][1]);
            bi[j][1] = c0 ? bi[j][0] : (c1 ? p  : bi[j][1]);
            bd[j][0] = c0 ? dd : bd[j][0];
            bi[j][0] = c0 ? p  : bi[j][0];
        }
    }

    // per-voxel tail: wave merge, interpolation, grouped conv
    #pragma unroll
    for (int j = 0; j < BS; ++j) {
        const int g = wv + 4 * (T0 + j);     // wave-uniform
        if (g < GVOX) {
            float d0 = bd[j][0], d1 = bd[j][1], d2 = bd[j][2];
            int   i0 = bi[j][0], i1 = bi[j][1], i2 = bi[j][2];

            for (int s = 1; s < 64; s <<= 1) {
                const float e0 = __shfl_xor(d0, s);
                const float e1 = __shfl_xor(d1, s);
                const float e2 = __shfl_xor(d2, s);
                const int   j0 = __shfl_xor(i0, s);
                const int   j1 = __shfl_xor(i1, s);
                const int   j2 = __shfl_xor(i2, s);
                merge3(d0, d1, d2, i0, i1, i2, e0, j0);
                merge3(d0, d1, d2, i0, i1, i2, e1, j1);
                merge3(d0, d1, d2, i0, i1, i2, e2, j2);
            }

            const float r0 = 1.0f / (d0 + 1e-8f);
            const float r1 = 1.0f / (d1 + 1e-8f);
            const float r2 = 1.0f / (d2 + 1e-8f);
            const float rs = fmaxf((r0 + r1) + r2, 1e-8f);
            const float w0 = r0 / rs, w1 = r1 / rs, w2 = r2 / rs;
            const bool  empty = !(d0 < INF);
            const int s0 = (i0 < NPTS) ? i0 : 0;
            const int s1 = (i1 < NPTS) ? i1 : 0;
            const int s2 = (i2 < NPTS) ? i2 : 0;

            float fval = 0.0f;
            if (lane < CRED) {
                const float* Fb = sfeat + b * (NPTS * 128) + lane;
                const float* p0 = Fb + s0 * 128;
                const float* p1 = Fb + s1 * 128;
                const float* p2 = Fb + s2 * 128;
                const float f0 = ((p0[0] + p0[32]) + p0[64]) + p0[96];
                const float f1 = ((p1[0] + p1[32]) + p1[64]) + p1[96];
                const float f2 = ((p2[0] + p2[32]) + p2[64]) + p2[96];
                fval = (w0 * f0 + w1 * f1) + w2 * f2;
            } else if (lane < CIG) {
                const int jj = lane - 32;
                const int kk = jj / 3, ax = jj - 3 * kk;
                const int ik = (kk == 0) ? s0 : ((kk == 1) ? s1 : s2);
                const float cc = (ax == 0) ? cx[j] : ((ax == 1) ? cy[j] : cz[j]);
                fval = cc - spts[ik * 3 + ax];
            }
            if (empty) fval = 0.0f;

            // conv: lane ch accumulates over 41 inputs via shfl broadcast
            // (uniform control flow; weight address clamped with lane&31)
            float acc = 0.0f;
            const float* wrow = wT + g * (CIG * CAGG) + (lane & 31);
            #pragma unroll
            for (int i = 0; i < CIG; ++i) {
                const float bc = __shfl(fval, i);
                acc += bc * wrow[i * CAGG];
            }
            if (lane < CAGG) {
                const int ch = g * CAGG + lane;
                xout[m * GCH + ch] = fmaxf(acc + bb1[ch], 0.0f);
            }
        }
    }
}

// ---------------------------------------------------------------------------
// Kernel 1: block = one target point m; wave wv owns voxels g = wv+4t
// processed in two register-friendly batches (t=0..3, t=4..6).
// ---------------------------------------------------------------------------
__global__ __launch_bounds__(256) void vpa_main(
    const float* __restrict__ sxyz,
    const float* __restrict__ sfeat,
    const float* __restrict__ nxyz,
    const float* __restrict__ ws,     // wT, bb1
    float* __restrict__ xout)
{
    __shared__ float spts[NPTS * 3];  // 24 KB

    const int m    = blockIdx.x;
    const int b    = m >> 9;
    const int tid  = threadIdx.x;
    const int lane = tid & 63;
    const int wv   = tid >> 6;

    const float* sx = sxyz + b * (NPTS * 3);
    for (int j = tid; j < NPTS * 3; j += 256) spts[j] = sx[j];

    const float nx = nxyz[m * 3 + 0];
    const float ny = nxyz[m * 3 + 1];
    const float nz = nxyz[m * 3 + 2];
    __syncthreads();

    const float* wT  = ws + WS_WT;
    const float* bb1 = ws + WS_BB1;

    process_batch<4, 0>(wv, lane, b, m, nx, ny, nz, spts, sfeat, wT, bb1, xout);
    process_batch<3, 4>(wv, lane, b, m, nx, ny, nz, spts, sfeat, wT, bb1, xout);
}

// ---------------------------------------------------------------------------
// Kernel 2: post MLP  out = relu(x @ wp2^T + bb2)
// block = 4 rows; threads = (il = i-lane 0..15) x (og = 0..15)
// two sequential o-halves with acc[4][4] keep peak regs ~46 (no spill at 64).
// ---------------------------------------------------------------------------
__global__ __launch_bounds__(256) void vpa_post(
    const float* __restrict__ xin,    // (1024,864)
    const float* __restrict__ ws,     // wp2, bb2
    float* __restrict__ out)          // (1024,128)
{
    __shared__ __align__(16) float xs[4 * GCH];   // 13.8 KB

    const int mb  = blockIdx.x * 4;
    const int tid = threadIdx.x;
    const float* wp2 = ws + WS_WP2;
    const float* bb2 = ws + WS_BB2;

    for (int j = tid; j < 4 * GCH; j += 256) xs[j] = xin[mb * GCH + j];
    __syncthreads();

    const int il = tid & 15;          // i-lane
    const int og = tid >> 4;          // 0..15

    #pragma unroll
    for (int oh = 0; oh < 2; ++oh) {
        float acc[4][4];
        #pragma unroll
        for (int oo = 0; oo < 4; ++oo)
            #pragma unroll
            for (int mm = 0; mm < 4; ++mm) acc[oo][mm] = 0.0f;

        for (int jj = 0; jj < 14; ++jj) {
            const int i4 = il + 16 * jj;
            if (i4 < 216) {
                const int i = i4 * 4;
                const float4 x0 = *(const float4*)&xs[0 * GCH + i];
                const float4 x1 = *(const float4*)&xs[1 * GCH + i];
                const float4 x2 = *(const float4*)&xs[2 * GCH + i];
                const float4 x3 = *(const float4*)&xs[3 * GCH + i];
                #pragma unroll
                for (int oo = 0; oo < 4; ++oo) {
                    const int o = (oh * 4 + oo) * 16 + og;
                    const float4 w = *(const float4*)&wp2[o * GCH + i];
                    acc[oo][0] += x0.x * w.x + x0.y * w.y + x0.z * w.z + x0.w * w.w;
                    acc[oo][1] += x1.x * w.x + x1.y * w.y + x1.z * w.z + x1.w * w.w;
                    acc[oo][2] += x2.x * w.x + x2.y * w.y + x2.z * w.z + x2.w * w.w;
                    acc[oo][3] += x3.x * w.x + x3.y * w.y + x3.z * w.z + x3.w * w.w;
                }
            }
        }

        // reduce over the 16 i-lanes (lanes grouped 16-consecutive per og)
        #pragma unroll
        for (int s = 1; s < 16; s <<= 1)
            #pragma unroll
            for (int oo = 0; oo < 4; ++oo)
                #pragma unroll
                for (int mm = 0; mm < 4; ++mm)
                    acc[oo][mm] += __shfl_xor(acc[oo][mm], s);

        if (il == 0) {
            #pragma unroll
            for (int oo = 0; oo < 4; ++oo) {
                const int o = (oh * 4 + oo) * 16 + og;
                const float bias = bb2[o];
                #pragma unroll
                for (int mm = 0; mm < 4; ++mm)
                    out[(mb + mm) * CPOST + o] = fmaxf(acc[oo][mm] + bias, 0.0f);
            }
        }
    }
}

// ---------------------------------------------------------------------------
extern "C" void kernel_launch(void* const* d_in, const int* in_sizes, int n_in,
                              void* d_out, int out_size, void* d_ws, size_t ws_size,
                              hipStream_t stream) {
    const float* sxyz  = (const float*)d_in[0];
    const float* sfeat = (const float*)d_in[1];
    const float* nxyz  = (const float*)d_in[2];
    const float* wgrp  = (const float*)d_in[3];
    const float* g1    = (const float*)d_in[4];
    const float* b1    = (const float*)d_in[5];
    const float* m1    = (const float*)d_in[6];
    const float* v1    = (const float*)d_in[7];
    const float* wp    = (const float*)d_in[8];
    const float* g2    = (const float*)d_in[9];
    const float* b2    = (const float*)d_in[10];
    const float* m2    = (const float*)d_in[11];
    const float* v2    = (const float*)d_in[12];

    float* ws   = (float*)d_ws;
    float* xbuf = ws + WS_XBUF;
    float* outp = (float*)d_out;

    hipLaunchKernelGGL(vpa_prep, dim3(575), dim3(256), 0, stream,
                       wgrp, g1, b1, m1, v1, wp, g2, b2, m2, v2, ws);
    hipLaunchKernelGGL(vpa_main, dim3(BM_TOT), dim3(256), 0, stream,
                       sxyz, sfeat, nxyz, ws, xbuf);
    hipLaunchKernelGGL(vpa_post, dim3(BM_TOT / 4), dim3(256), 0, stream,
                       xbuf, ws, outp);
}

// Round 7
// 206.780 us; speedup vs baseline: 1.0833x; 1.0280x over previous
//
#include <hip/hip_runtime.h>

// Problem constants
#define BATCH   2
#define NPTS    2048
#define MPTS    512
#define BM_TOT  1024     // BATCH*MPTS
#define GVOX    27
#define CRED    32
#define CIG     41       // CRED + 9
#define CAGG    32
#define GCH     864      // GVOX*CAGG
#define CPOST   128
#define QRF     4.8f
// Safe gate-free threshold: gated points have d2 > 4.8^2 = 23.04 (strict);
// f32 rounding margin ~1e-5, so 23.0 is conservatively safe on both sides.
#define GATE_THR 23.0f
#define MULT    1.6000000238418579f   // f32(2.0*2.4/3.0)

// d_ws float layout
#define WS_XBUF  0                      // 1024*864
#define WS_WT    884736                 // 27*41*32 = 35424  (transposed, BN1-scaled)
#define WS_BB1   920160                 // 864
#define WS_WP2   921024                 // 128*864 (BN2-scaled)
#define WS_BB2   1031616                // 128

// ---------------------------------------------------------------------------
// Prep: fold BN1 into transposed group weights, BN2 into w_post (unchanged r6)
// ---------------------------------------------------------------------------
__global__ __launch_bounds__(256) void vpa_prep(
    const float* __restrict__ wgrp,
    const float* __restrict__ g1, const float* __restrict__ b1,
    const float* __restrict__ m1, const float* __restrict__ v1,
    const float* __restrict__ wp,
    const float* __restrict__ g2, const float* __restrict__ b2,
    const float* __restrict__ m2, const float* __restrict__ v2,
    float* __restrict__ ws)
{
    const int idx = blockIdx.x * 256 + threadIdx.x;
    if (idx < 35424) {                       // wT[g][i][o] = wgrp[g][o][i]*sc1
        const int o = idx & 31;
        const int r = idx >> 5;              // g*41 + i
        const int g = r / 41;
        const int ch = g * CAGG + o;
        const float sc = g1[ch] * rsqrtf(v1[ch] + 1e-5f);
        ws[WS_WT + idx] = wgrp[ch * CIG + (r - g * 41)] * sc;
    }
    int j = idx - 35424;
    if (j >= 0 && j < GCH) {                 // bb1
        const float sc = g1[j] * rsqrtf(v1[j] + 1e-5f);
        ws[WS_BB1 + j] = b1[j] - sc * m1[j];
    }
    j = idx - (35424 + GCH);
    if (j >= 0 && j < CPOST * GCH) {         // wp2[o][i] = wp[o][i]*sc2[o]
        const int o = j / GCH;
        const float sc = g2[o] * rsqrtf(v2[o] + 1e-5f);
        ws[WS_WP2 + j] = wp[j] * sc;
    }
    j = idx - (35424 + GCH + CPOST * GCH);
    if (j >= 0 && j < CPOST) {               // bb2
        const float sc = g2[j] * rsqrtf(v2[j] + 1e-5f);
        ws[WS_BB2 + j] = b2[j] - sc * m2[j];
    }
}

// lexicographic (d, idx) sorted-3 insert
__device__ __forceinline__ void merge3(float& d0, float& d1, float& d2,
                                       int& i0, int& i1, int& i2,
                                       float e, int jj) {
    const bool c0 = (e < d0) || (e == d0 && jj < i0);
    const bool c1 = (e < d1) || (e == d1 && jj < i1);
    const bool c2 = (e < d2) || (e == d2 && jj < i2);
    d2 = c1 ? d1 : (c2 ? e : d2);  i2 = c1 ? i1 : (c2 ? jj : i2);
    d1 = c0 ? d0 : (c1 ? e : d1);  i1 = c0 ? i0 : (c1 ? jj : i1);
    d0 = c0 ? e : d0;              i0 = c0 ? jj : i0;
}

// full 64-lane butterfly merge of per-lane sorted-3 lists
__device__ __forceinline__ void wave_merge(float& d0, float& d1, float& d2,
                                           int& i0, int& i1, int& i2) {
    for (int s = 1; s < 64; s <<= 1) {
        const float e0 = __shfl_xor(d0, s);
        const float e1 = __shfl_xor(d1, s);
        const float e2 = __shfl_xor(d2, s);
        const int   j0 = __shfl_xor(i0, s);
        const int   j1 = __shfl_xor(i1, s);
        const int   j2 = __shfl_xor(i2, s);
        merge3(d0, d1, d2, i0, i1, i2, e0, j0);
        merge3(d0, d1, d2, i0, i1, i2, e1, j1);
        merge3(d0, d1, d2, i0, i1, i2, e2, j2);
    }
}

// ---------------------------------------------------------------------------
// One batch of BS voxels for wave wv. Hot scan is GATE-FREE (cheby dropped:
// cheby<=||d|| so gated points have d2>23.04; if merged 3rd-best <=23.0 the
// gated result is provably identical). Rare wave-uniform slow path redoes
// one voxel with the exact gate.
// ---------------------------------------------------------------------------
template<int BS, int T0>
__device__ __forceinline__ void process_batch(
    const int wv, const int lane, const int b, const int m,
    const float nx, const float ny, const float nz,
    const float* __restrict__ spts,
    const float* __restrict__ sfeat,
    const float* __restrict__ wT,
    const float* __restrict__ bb1,
    float* __restrict__ xout)
{
    const float INF = __builtin_inff();

    float cx[BS], cy[BS], cz[BS];
    float bd[BS][3];
    int   bi[BS][3];

    #pragma unroll
    for (int j = 0; j < BS; ++j) {
        const int g = wv + 4 * (T0 + j);
        if (g < GVOX) {
            const int gi = g / 9, rem = g - gi * 9;
            const int gj = rem / 3, gk = rem - gj * 3;
            cx[j] = nx + (((float)gi + 0.5f) * MULT - 2.4f);
            cy[j] = ny + (((float)gj + 0.5f) * MULT - 2.4f);
            cz[j] = nz + (((float)gk + 0.5f) * MULT - 2.4f);
        } else {
            cx[j] = cy[j] = cz[j] = 1e18f;   // results discarded
        }
        bd[j][0] = bd[j][1] = bd[j][2] = INF;
        bi[j][0] = bi[j][1] = bi[j][2] = 0x7fffffff;
    }

    // gate-free scan: load each point once, update BS voxels
    #pragma unroll 2
    for (int k = 0; k < 32; ++k) {
        const int p  = (k << 6) + lane;
        const int p3 = p * 3;
        const float px = spts[p3 + 0];
        const float py = spts[p3 + 1];
        const float pz = spts[p3 + 2];
        #pragma unroll
        for (int j = 0; j < BS; ++j) {
            const float dx = cx[j] - px;
            const float dy = cy[j] - py;
            const float dz = cz[j] - pz;
            const float dd = __fadd_rn(__fadd_rn(__fmul_rn(dx, dx),
                                                 __fmul_rn(dy, dy)),
                                       __fmul_rn(dz, dz));
            const bool c0 = dd < bd[j][0], c1 = dd < bd[j][1], c2 = dd < bd[j][2];
            bd[j][2] = c1 ? bd[j][1] : (c2 ? dd : bd[j][2]);
            bi[j][2] = c1 ? bi[j][1] : (c2 ? p  : bi[j][2]);
            bd[j][1] = c0 ? bd[j][0] : (c1 ? dd : bd[j][1]);
            bi[j][1] = c0 ? bi[j][0] : (c1 ? p  : bi[j][1]);
            bd[j][0] = c0 ? dd : bd[j][0];
            bi[j][0] = c0 ? p  : bi[j][0];
        }
    }

    // per-voxel tail
    #pragma unroll
    for (int j = 0; j < BS; ++j) {
        const int g = wv + 4 * (T0 + j);     // wave-uniform
        if (g < GVOX) {
            float d0 = bd[j][0], d1 = bd[j][1], d2 = bd[j][2];
            int   i0 = bi[j][0], i1 = bi[j][1], i2 = bi[j][2];
            wave_merge(d0, d1, d2, i0, i1, i2);

            // after full merge every lane holds the same top-3 -> uniform branch
            if (d2 > GATE_THR) {
                // SLOW PATH (rare): exact gated rescan for this voxel
                d0 = d1 = d2 = INF;
                i0 = i1 = i2 = 0x7fffffff;
                for (int k = 0; k < 32; ++k) {
                    const int p  = (k << 6) + lane;
                    const int p3 = p * 3;
                    const float dx = cx[j] - spts[p3 + 0];
                    const float dy = cy[j] - spts[p3 + 1];
                    const float dz = cz[j] - spts[p3 + 2];
                    float dd = __fadd_rn(__fadd_rn(__fmul_rn(dx, dx),
                                                   __fmul_rn(dy, dy)),
                                         __fmul_rn(dz, dz));
                    const float ch = fmaxf(fmaxf(fabsf(dx), fabsf(dy)), fabsf(dz));
                    dd = (ch <= QRF) ? dd : INF;
                    const bool c0 = dd < d0, c1 = dd < d1, c2 = dd < d2;
                    d2 = c1 ? d1 : (c2 ? dd : d2);  i2 = c1 ? i1 : (c2 ? p : i2);
                    d1 = c0 ? d0 : (c1 ? dd : d1);  i1 = c0 ? i0 : (c1 ? p : i1);
                    d0 = c0 ? dd : d0;              i0 = c0 ? p  : i0;
                }
                wave_merge(d0, d1, d2, i0, i1, i2);
            }

            const float r0 = 1.0f / (d0 + 1e-8f);
            const float r1 = 1.0f / (d1 + 1e-8f);
            const float r2 = 1.0f / (d2 + 1e-8f);
            const float rs = fmaxf((r0 + r1) + r2, 1e-8f);
            const float w0 = r0 / rs, w1 = r1 / rs, w2 = r2 / rs;
            const bool  empty = !(d0 < INF);
            const int s0 = (i0 < NPTS) ? i0 : 0;
            const int s1 = (i1 < NPTS) ? i1 : 0;
            const int s2 = (i2 < NPTS) ? i2 : 0;

            float fval = 0.0f;
            if (lane < CRED) {
                const float* Fb = sfeat + b * (NPTS * 128) + lane;
                const float* p0 = Fb + s0 * 128;
                const float* p1 = Fb + s1 * 128;
                const float* p2 = Fb + s2 * 128;
                const float f0 = ((p0[0] + p0[32]) + p0[64]) + p0[96];
                const float f1 = ((p1[0] + p1[32]) + p1[64]) + p1[96];
                const float f2 = ((p2[0] + p2[32]) + p2[64]) + p2[96];
                fval = (w0 * f0 + w1 * f1) + w2 * f2;
            } else if (lane < CIG) {
                const int jj = lane - 32;
                const int kk = jj / 3, ax = jj - 3 * kk;
                const int ik = (kk == 0) ? s0 : ((kk == 1) ? s1 : s2);
                const float cc = (ax == 0) ? cx[j] : ((ax == 1) ? cy[j] : cz[j]);
                fval = cc - spts[ik * 3 + ax];
            }
            if (empty) fval = 0.0f;

            // grouped conv via shfl broadcast (uniform control flow)
            float acc = 0.0f;
            const float* wrow = wT + g * (CIG * CAGG) + (lane & 31);
            #pragma unroll
            for (int i = 0; i < CIG; ++i) {
                const float bc = __shfl(fval, i);
                acc += bc * wrow[i * CAGG];
            }
            if (lane < CAGG) {
                const int ch = g * CAGG + lane;
                xout[m * GCH + ch] = fmaxf(acc + bb1[ch], 0.0f);
            }
        }
    }
}

// ---------------------------------------------------------------------------
// Kernel 1: block = one target point m; wave wv owns voxels g = wv+4t
// ---------------------------------------------------------------------------
__global__ __launch_bounds__(256) void vpa_main(
    const float* __restrict__ sxyz,
    const float* __restrict__ sfeat,
    const float* __restrict__ nxyz,
    const float* __restrict__ ws,     // wT, bb1
    float* __restrict__ xout)
{
    __shared__ float spts[NPTS * 3];  // 24 KB

    const int m    = blockIdx.x;
    const int b    = m >> 9;
    const int tid  = threadIdx.x;
    const int lane = tid & 63;
    const int wv   = tid >> 6;

    const float* sx = sxyz + b * (NPTS * 3);
    for (int j = tid; j < NPTS * 3; j += 256) spts[j] = sx[j];

    const float nx = nxyz[m * 3 + 0];
    const float ny = nxyz[m * 3 + 1];
    const float nz = nxyz[m * 3 + 2];
    __syncthreads();

    const float* wT  = ws + WS_WT;
    const float* bb1 = ws + WS_BB1;

    process_batch<4, 0>(wv, lane, b, m, nx, ny, nz, spts, sfeat, wT, bb1, xout);
    process_batch<3, 4>(wv, lane, b, m, nx, ny, nz, spts, sfeat, wT, bb1, xout);
}

// ---------------------------------------------------------------------------
// Kernel 2: post MLP (unchanged from r6)
// ---------------------------------------------------------------------------
__global__ __launch_bounds__(256) void vpa_post(
    const float* __restrict__ xin,    // (1024,864)
    const float* __restrict__ ws,     // wp2, bb2
    float* __restrict__ out)          // (1024,128)
{
    __shared__ __align__(16) float xs[4 * GCH];   // 13.8 KB

    const int mb  = blockIdx.x * 4;
    const int tid = threadIdx.x;
    const float* wp2 = ws + WS_WP2;
    const float* bb2 = ws + WS_BB2;

    for (int j = tid; j < 4 * GCH; j += 256) xs[j] = xin[mb * GCH + j];
    __syncthreads();

    const int il = tid & 15;          // i-lane
    const int og = tid >> 4;          // 0..15

    #pragma unroll
    for (int oh = 0; oh < 2; ++oh) {
        float acc[4][4];
        #pragma unroll
        for (int oo = 0; oo < 4; ++oo)
            #pragma unroll
            for (int mm = 0; mm < 4; ++mm) acc[oo][mm] = 0.0f;

        for (int jj = 0; jj < 14; ++jj) {
            const int i4 = il + 16 * jj;
            if (i4 < 216) {
                const int i = i4 * 4;
                const float4 x0 = *(const float4*)&xs[0 * GCH + i];
                const float4 x1 = *(const float4*)&xs[1 * GCH + i];
                const float4 x2 = *(const float4*)&xs[2 * GCH + i];
                const float4 x3 = *(const float4*)&xs[3 * GCH + i];
                #pragma unroll
                for (int oo = 0; oo < 4; ++oo) {
                    const int o = (oh * 4 + oo) * 16 + og;
                    const float4 w = *(const float4*)&wp2[o * GCH + i];
                    acc[oo][0] += x0.x * w.x + x0.y * w.y + x0.z * w.z + x0.w * w.w;
                    acc[oo][1] += x1.x * w.x + x1.y * w.y + x1.z * w.z + x1.w * w.w;
                    acc[oo][2] += x2.x * w.x + x2.y * w.y + x2.z * w.z + x2.w * w.w;
                    acc[oo][3] += x3.x * w.x + x3.y * w.y + x3.z * w.z + x3.w * w.w;
                }
            }
        }

        #pragma unroll
        for (int s = 1; s < 16; s <<= 1)
            #pragma unroll
            for (int oo = 0; oo < 4; ++oo)
                #pragma unroll
                for (int mm = 0; mm < 4; ++mm)
                    acc[oo][mm] += __shfl_xor(acc[oo][mm], s);

        if (il == 0) {
            #pragma unroll
            for (int oo = 0; oo < 4; ++oo) {
                const int o = (oh * 4 + oo) * 16 + og;
                const float bias = bb2[o];
                #pragma unroll
                for (int mm = 0; mm < 4; ++mm)
                    out[(mb + mm) * CPOST + o] = fmaxf(acc[oo][mm] + bias, 0.0f);
            }
        }
    }
}

// ---------------------------------------------------------------------------
extern "C" void kernel_launch(void* const* d_in, const int* in_sizes, int n_in,
                              void* d_out, int out_size, void* d_ws, size_t ws_size,
                              hipStream_t stream) {
    const float* sxyz  = (const float*)d_in[0];
    const float* sfeat = (const float*)d_in[1];
    const float* nxyz  = (const float*)d_in[2];
    const float* wgrp  = (const float*)d_in[3];
    const float* g1    = (const float*)d_in[4];
    const float* b1    = (const float*)d_in[5];
    const float* m1    = (const float*)d_in[6];
    const float* v1    = (const float*)d_in[7];
    const float* wp    = (const float*)d_in[8];
    const float* g2    = (const float*)d_in[9];
    const float* b2    = (const float*)d_in[10];
    const float* m2    = (const float*)d_in[11];
    const float* v2    = (const float*)d_in[12];

    float* ws   = (float*)d_ws;
    float* xbuf = ws + WS_XBUF;
    float* outp = (float*)d_out;

    hipLaunchKernelGGL(vpa_prep, dim3(575), dim3(256), 0, stream,
                       wgrp, g1, b1, m1, v1, wp, g2, b2, m2, v2, ws);
    hipLaunchKernelGGL(vpa_main, dim3(BM_TOT), dim3(256), 0, stream,
                       sxyz, sfeat, nxyz, ws, xbuf);
    hipLaunchKernelGGL(vpa_post, dim3(BM_TOT / 4), dim3(256), 0, stream,
                       xbuf, ws, outp);
}